// Round 8
// baseline (293.995 us; speedup 1.0000x reference)
//
#include <hip/hip_runtime.h>
#include <hip/hip_bf16.h>

#define DIN 128
#define NEG_SLOPE 0.2f
#define PTILE 2048        // edges per partition tile
#define CVT_BLKS 289      // blocks of cvt work in the merged cvt+hist kernel
#define SCAP 2560         // per-subblock LDS edge capacity (avg 1024, sigma~28)
#define LDSP 136          // LDS row stride in ushorts (272B, 16B-aligned)

typedef __attribute__((ext_vector_type(8))) short bf16x8;   // 8 bf16 = 4 VGPRs
typedef __attribute__((ext_vector_type(8))) unsigned short u16x8;
typedef __attribute__((ext_vector_type(4))) float f32x4;
typedef __attribute__((ext_vector_type(2))) float f32x2;
typedef __attribute__((ext_vector_type(4))) unsigned int u32x4;

__device__ __forceinline__ ushort f2bf(float f) {
  unsigned u = __float_as_uint(f);
  u += 0x7FFFu + ((u >> 16) & 1u);   // round-to-nearest-even
  return (ushort)(u >> 16);
}
__device__ __forceinline__ float bf2f(ushort u) {
  return __uint_as_float((unsigned)u << 16);
}
// unpack 2 packed bf16 (one dword) -> f32x2 {elem0, elem1}
__device__ __forceinline__ f32x2 bfpair(unsigned u) {
  f32x2 r;
  r.x = __uint_as_float(u << 16);
  r.y = __uint_as_float(u & 0xFFFF0000u);
  return r;
}

// ---------------------------------------------------------------------------
// merged prep: blocks [0,CVT_BLKS) convert weights -> bf16 transposed;
// blocks [CVT_BLKS,...) build the 256-bucket dst histogram (bucket=dst>>8).
// ghist zeroed by hipMemsetAsync before this kernel.
// ---------------------------------------------------------------------------
__global__ __launch_bounds__(256) void cvt_hist_kernel(
    const float* __restrict__ Wl, const float* __restrict__ Wr,
    const float* __restrict__ W1, const float* __restrict__ W2,
    const float* __restrict__ W3,
    ushort* __restrict__ WlT, ushort* __restrict__ WrT,
    ushort* __restrict__ W1T, ushort* __restrict__ W2T,
    ushort* __restrict__ W3T,
    const int* __restrict__ ei, int* __restrict__ ghist, int E) {
  if (blockIdx.x < CVT_BLKS) {
    int i = blockIdx.x * 256 + threadIdx.x;
    if (i < 16384) {
      int k = i >> 7, c = i & 127; WlT[c * 128 + k] = f2bf(Wl[i]);
    } else if (i < 32768) {
      int j = i - 16384; int k = j >> 7, c = j & 127; WrT[c * 128 + k] = f2bf(Wr[j]);
    } else if (i < 49152) {
      int j = i - 32768; int k = j >> 7, c = j & 127; W1T[c * 128 + k] = f2bf(W1[j]);
    } else if (i < 65536) {
      int j = i - 49152; int k = j >> 7, c = j & 127; W2T[c * 128 + k] = f2bf(W2[j]);
    } else if (i < 73728) {
      int j = i - 65536; int k = j >> 6, c = j & 63; W3T[c * 128 + k] = f2bf(W3[j]);
    }
  } else {
    __shared__ int h[256];
    h[threadIdx.x] = 0;
    __syncthreads();
    int tile = blockIdx.x - CVT_BLKS;
    for (int e = tile * PTILE + threadIdx.x;
         e < min(E, (tile + 1) * PTILE); e += 256)
      atomicAdd(&h[ei[E + e] >> 8], 1);
    __syncthreads();
    if (h[threadIdx.x] > 0) atomicAdd(&ghist[threadIdx.x], h[threadIdx.x]);
  }
}

// 1 block: exclusive scan of ghist[256] -> cum[257]; cursor[b] = cum[b].
__global__ __launch_bounds__(256) void scan_small_kernel(
    const int* __restrict__ ghist, int* __restrict__ cum,
    int* __restrict__ cursor) {
  __shared__ int sh[256];
  int tid = threadIdx.x;
  int v = ghist[tid];
  sh[tid] = v;
  __syncthreads();
  for (int d = 1; d < 256; d <<= 1) {
    int t = (tid >= d) ? sh[tid - d] : 0;
    __syncthreads();
    sh[tid] += t;
    __syncthreads();
  }
  int exc = sh[tid] - v;
  cum[tid] = exc;
  cursor[tid] = exc;
  if (tid == 255) cum[256] = sh[255];
}

// ---------------------------------------------------------------------------
// MEGA kernel: blocks [0,nblk_lin) run the lin_lr MFMA GEMM; the rest run
// the partition pass (independent work, overlapped on one dispatch).
// ---------------------------------------------------------------------------
__global__ __launch_bounds__(256) void lin_partition_kernel(
    const float* __restrict__ x,
    const ushort* __restrict__ WlT, const float* __restrict__ bl,
    const ushort* __restrict__ WrT, const float* __restrict__ br,
    ushort* __restrict__ xl, ushort* __restrict__ xr, int n, int nblk_lin,
    const int* __restrict__ ei, unsigned* __restrict__ part,
    int* __restrict__ cursor, int E) {
  if ((int)blockIdx.x < nblk_lin) {
    // ---- lin_lr: xl = x@Wl+bl ; xr = x@Wr+br (bf16 out) ----
    const int tid = threadIdx.x;
    const int wv = tid >> 6, lane = tid & 63;
    const int m = lane & 15, quad = lane >> 4;
    const int colbase = (wv & 1) * 64;
    const int nodew = blockIdx.x * 32 + (wv >> 1) * 16;
    int arow = nodew + m; if (arow >= n) arow = n - 1;
    f32x4 accl[4], accr[4];
#pragma unroll
    for (int nt = 0; nt < 4; nt++) { accl[nt] = (f32x4){0,0,0,0}; accr[nt] = (f32x4){0,0,0,0}; }
#pragma unroll
    for (int kk = 0; kk < 4; kk++) {
      int k0 = kk * 32 + quad * 8;
      const float4* xp = (const float4*)(x + (long)arow * 128 + k0);
      float4 x0 = xp[0], x1 = xp[1];
      bf16x8 af;
      af[0] = (short)f2bf(x0.x); af[1] = (short)f2bf(x0.y);
      af[2] = (short)f2bf(x0.z); af[3] = (short)f2bf(x0.w);
      af[4] = (short)f2bf(x1.x); af[5] = (short)f2bf(x1.y);
      af[6] = (short)f2bf(x1.z); af[7] = (short)f2bf(x1.w);
#pragma unroll
      for (int nt = 0; nt < 4; nt++) {
        int brow = colbase + nt * 16 + m;
        bf16x8 bl8 = *(const bf16x8*)(WlT + brow * 128 + k0);
        bf16x8 br8 = *(const bf16x8*)(WrT + brow * 128 + k0);
        accl[nt] = __builtin_amdgcn_mfma_f32_16x16x32_bf16(af, bl8, accl[nt], 0, 0, 0);
        accr[nt] = __builtin_amdgcn_mfma_f32_16x16x32_bf16(af, br8, accr[nt], 0, 0, 0);
      }
    }
#pragma unroll
    for (int nt = 0; nt < 4; nt++) {
      int col = colbase + nt * 16 + m;
      float vbl = bl[col], vbr = br[col];
#pragma unroll
      for (int r = 0; r < 4; r++) {
        int node = nodew + quad * 4 + r;
        if (node < n) {
          xl[(long)node * 128 + col] = f2bf(accl[nt][r] + vbl);
          xr[(long)node * 128 + col] = f2bf(accr[nt][r] + vbr);
        }
      }
    }
  } else {
    // ---- partition: tile -> LDS bucket-grouped reorder -> dense runs ----
    __shared__ int hist[256], pref[256], sexcl[256], curs[256], gbase[256];
    __shared__ unsigned buf[PTILE];
    const int tid = threadIdx.x;
    const int tile0 = ((int)blockIdx.x - nblk_lin) * PTILE;
    const int tcount = min(PTILE, E - tile0);
    hist[tid] = 0;
    __syncthreads();
    unsigned pk[PTILE / 256];
    int cnt = 0;
    for (int i = tid; i < tcount; i += 256) {
      int e = tile0 + i;
      int s = ei[e], d = ei[E + e];
      unsigned p = ((unsigned)d << 16) | (unsigned)s;
      pk[cnt++] = p;
      atomicAdd(&hist[d >> 8], 1);
    }
    __syncthreads();
    int v = hist[tid];
    pref[tid] = v;
    __syncthreads();
    for (int d = 1; d < 256; d <<= 1) {
      int t = (tid >= d) ? pref[tid - d] : 0;
      __syncthreads();
      pref[tid] += t;
      __syncthreads();
    }
    int exc = pref[tid] - v;
    sexcl[tid] = exc;
    curs[tid] = exc;
    gbase[tid] = (v > 0) ? atomicAdd(&cursor[tid], v) : 0;
    __syncthreads();
    for (int j = 0; j < cnt; j++) {
      int b = pk[j] >> 24;
      int pos = atomicAdd(&curs[b], 1);
      buf[pos] = pk[j];
    }
    __syncthreads();
    for (int i = tid; i < tcount; i += 256) {
      unsigned p = buf[i];
      int b = p >> 24;
      part[gbase[b] + (i - sexcl[b])] = p;
    }
  }
}

// ---------------------------------------------------------------------------
// FUSED fine + GATv2 aggregation + 3-layer MLP.
// One block = one 64-node sub-bucket (grid = nbuck*4, 256 threads, 4 waves).
// Phase 1: scan bucket's part segment (x2, L2-hot), build per-node edge
//          lists in LDS (ushort src) + offsets (fine_kernel, LDS-resident).
// Phase 2: wave per 16 nodes; R7's packed online aggregation; h rows
//          (bf16, bg added) written to LDS hbuf — never to global.
// Phase 3: MFMA MLP on the block's 64 rows straight from LDS; write out.
// Heterogeneous phases across co-resident blocks overlap MFMA with gathers.
// ---------------------------------------------------------------------------
__global__ __launch_bounds__(256) void aggr_mlp_kernel(
    const ushort* __restrict__ xl, const ushort* __restrict__ xr,
    const float* __restrict__ att, const float* __restrict__ bg,
    const unsigned* __restrict__ part, const int* __restrict__ cum,
    const ushort* __restrict__ W1T, const float* __restrict__ b1,
    const ushort* __restrict__ W2T, const float* __restrict__ b2,
    const ushort* __restrict__ W3T, const float* __restrict__ b3,
    float* __restrict__ out, int n) {
  __shared__ int hist[64], offs[65], curs[64];
  __shared__ ushort ssrc[SCAP];
  __shared__ ushort hbuf[64][LDSP];
  const int tid = threadIdx.x;
  const int b = blockIdx.x >> 2, sub = blockIdx.x & 3;
  const int node_lo = (b << 8) + (sub << 6);
  const int dlo = node_lo, dhi = node_lo + 64;
  const int seg0 = cum[b];
  const int len = cum[b + 1] - seg0;

  // ---- phase 1: per-node hist -> scan -> LDS edge lists ----
  if (tid < 64) hist[tid] = 0;
  __syncthreads();
  for (int i = tid; i < len; i += 256) {
    int d = (int)(part[seg0 + i] >> 16);
    if (d >= dlo && d < dhi) atomicAdd(&hist[d - dlo], 1);
  }
  __syncthreads();
  if (tid < 64) {
    int v = hist[tid];
    int s = v;
#pragma unroll
    for (int dd = 1; dd < 64; dd <<= 1) {
      int t = __shfl_up(s, dd);
      if (tid >= dd) s += t;
    }
    offs[tid] = s - v;
    curs[tid] = s - v;
    if (tid == 63) offs[64] = s;
  }
  __syncthreads();
  for (int i = tid; i < len; i += 256) {
    unsigned p = part[seg0 + i];
    int d = (int)(p >> 16);
    if (d >= dlo && d < dhi) {
      int pos = atomicAdd(&curs[d - dlo], 1);
      if (pos < SCAP) ssrc[pos] = (ushort)(p & 0xFFFFu);
    }
  }
  __syncthreads();

  // ---- phase 2: per-node online-softmax aggregation (wave per 16 nodes) ----
  const int wv = tid >> 6, lane = tid & 63;
  const int eg = lane >> 4, sl = lane & 15;
  f32x2 av2[4], gv2[4];
  {
    const float4* ap = (const float4*)(att + sl * 8);
    float4 a0 = ap[0], a1 = ap[1];
    av2[0] = (f32x2){a0.x, a0.y}; av2[1] = (f32x2){a0.z, a0.w};
    av2[2] = (f32x2){a1.x, a1.y}; av2[3] = (f32x2){a1.z, a1.w};
    const float4* bp = (const float4*)(bg + sl * 8);
    float4 g0 = bp[0], g1 = bp[1];
    gv2[0] = (f32x2){g0.x, g0.y}; gv2[1] = (f32x2){g0.z, g0.w};
    gv2[2] = (f32x2){g1.x, g1.y}; gv2[3] = (f32x2){g1.z, g1.w};
  }
  for (int t = 0; t < 16; t++) {
    const int ln = (wv << 4) + t;
    const int node = node_lo + ln;
    if (node >= n) {
      if (eg == 0) {
        u16x8 z;
#pragma unroll
        for (int j = 0; j < 8; j++) z[j] = 0;
        *(u16x8*)(&hbuf[ln][sl * 8]) = z;
      }
      continue;
    }
    f32x2 r2[4], acc2[4];
    u32x4 rv = *(const u32x4*)(xr + (long)node * 128 + sl * 8);
    u32x4 lv = *(const u32x4*)(xl + (long)node * 128 + sl * 8);
    float denom;
    {
      f32x2 t2 = {0.f, 0.f};
      f32x2 l2[4];
#pragma unroll
      for (int jp = 0; jp < 4; jp++) {
        r2[jp] = bfpair(rv[jp]);
        l2[jp] = bfpair(lv[jp]);
        f32x2 v = l2[jp] + r2[jp];
        t2 += __builtin_elementwise_max(v, NEG_SLOPE * v) * av2[jp];
      }
      float tt = t2.x + t2.y;
#pragma unroll
      for (int off = 1; off < 16; off <<= 1) tt += __shfl_xor(tt, off);
      float es = __expf(tt);             // self-loop weight
      denom = (eg == 0) ? es : 0.f;
#pragma unroll
      for (int jp = 0; jp < 4; jp++)
        acc2[jp] = (eg == 0) ? es * l2[jp] : (f32x2){0.f, 0.f};
    }
    const int beg = min(offs[ln], SCAP);
    const int end = min(offs[ln + 1], SCAP);
    for (int p = beg; p < end; p += 8) {
      int ia = p + 2 * eg;
      bool va = ia < end, vb = ia + 1 < end;
      int sa = va ? (int)ssrc[ia] : node;
      int sb = vb ? (int)ssrc[ia + 1] : node;
      u32x4 uva = *(const u32x4*)(xl + (long)sa * 128 + sl * 8);
      u32x4 uvb = *(const u32x4*)(xl + (long)sb * 128 + sl * 8);
      f32x2 ua2[4], ub2[4];
      f32x2 ta2 = {0.f, 0.f}, tb2 = {0.f, 0.f};
#pragma unroll
      for (int jp = 0; jp < 4; jp++) {
        ua2[jp] = bfpair(uva[jp]);
        ub2[jp] = bfpair(uvb[jp]);
        f32x2 va2 = ua2[jp] + r2[jp];
        f32x2 vb2 = ub2[jp] + r2[jp];
        ta2 += __builtin_elementwise_max(va2, NEG_SLOPE * va2) * av2[jp];
        tb2 += __builtin_elementwise_max(vb2, NEG_SLOPE * vb2) * av2[jp];
      }
      float ta = ta2.x + ta2.y, tb = tb2.x + tb2.y;
#pragma unroll
      for (int off = 1; off < 16; off <<= 1) {
        ta += __shfl_xor(ta, off);
        tb += __shfl_xor(tb, off);
      }
      float ea = va ? __expf(ta) : 0.f;
      float eb = vb ? __expf(tb) : 0.f;
      denom += ea + eb;
#pragma unroll
      for (int jp = 0; jp < 4; jp++)
        acc2[jp] += ea * ua2[jp] + eb * ub2[jp];
    }
    // combine the 4 edge-subgroup replicas
#pragma unroll
    for (int jp = 0; jp < 4; jp++) {
      acc2[jp].x += __shfl_xor(acc2[jp].x, 16);
      acc2[jp].y += __shfl_xor(acc2[jp].y, 16);
      acc2[jp].x += __shfl_xor(acc2[jp].x, 32);
      acc2[jp].y += __shfl_xor(acc2[jp].y, 32);
    }
    denom += __shfl_xor(denom, 16);
    denom += __shfl_xor(denom, 32);
    if (eg == 0) {
      float inv = 1.0f / denom;
      u16x8 o;
#pragma unroll
      for (int jp = 0; jp < 4; jp++) {
        f32x2 hv = acc2[jp] * inv + gv2[jp];
        o[2 * jp]     = f2bf(hv.x);
        o[2 * jp + 1] = f2bf(hv.y);
      }
      *(u16x8*)(&hbuf[ln][sl * 8]) = o;
    }
  }
  __syncthreads();

  // ---- phase 3: 3-layer MFMA MLP on the block's 64 LDS rows ----
  const int m = lane & 15, quad = lane >> 4;
  const int arow = (wv << 4) + m;          // LDS row for A-fragment
  bf16x8 af[4];
  f32x4 acc[8];
  // layer 1: hbuf @ W1 + b1, relu -> hbuf
#pragma unroll
  for (int kk = 0; kk < 4; kk++)
    af[kk] = *(const bf16x8*)(&hbuf[arow][kk * 32 + quad * 8]);
#pragma unroll
  for (int nt = 0; nt < 8; nt++) acc[nt] = (f32x4){0,0,0,0};
#pragma unroll
  for (int kk = 0; kk < 4; kk++) {
    int k0 = kk * 32 + quad * 8;
#pragma unroll
    for (int nt = 0; nt < 8; nt++) {
      bf16x8 b8 = *(const bf16x8*)(W1T + (nt * 16 + m) * 128 + k0);
      acc[nt] = __builtin_amdgcn_mfma_f32_16x16x32_bf16(af[kk], b8, acc[nt], 0, 0, 0);
    }
  }
  __syncthreads();
#pragma unroll
  for (int nt = 0; nt < 8; nt++) {
    int col = nt * 16 + m;
    float bv = b1[col];
#pragma unroll
    for (int r = 0; r < 4; r++)
      hbuf[(wv << 4) + quad * 4 + r][col] = f2bf(fmaxf(acc[nt][r] + bv, 0.f));
  }
  __syncthreads();
  // layer 2: hbuf @ W2 + b2, relu -> hbuf
#pragma unroll
  for (int kk = 0; kk < 4; kk++)
    af[kk] = *(const bf16x8*)(&hbuf[arow][kk * 32 + quad * 8]);
#pragma unroll
  for (int nt = 0; nt < 8; nt++) acc[nt] = (f32x4){0,0,0,0};
#pragma unroll
  for (int kk = 0; kk < 4; kk++) {
    int k0 = kk * 32 + quad * 8;
#pragma unroll
    for (int nt = 0; nt < 8; nt++) {
      bf16x8 b8 = *(const bf16x8*)(W2T + (nt * 16 + m) * 128 + k0);
      acc[nt] = __builtin_amdgcn_mfma_f32_16x16x32_bf16(af[kk], b8, acc[nt], 0, 0, 0);
    }
  }
  __syncthreads();
#pragma unroll
  for (int nt = 0; nt < 8; nt++) {
    int col = nt * 16 + m;
    float bv = b2[col];
#pragma unroll
    for (int r = 0; r < 4; r++)
      hbuf[(wv << 4) + quad * 4 + r][col] = f2bf(fmaxf(acc[nt][r] + bv, 0.f));
  }
  __syncthreads();
  // layer 3: hbuf @ W3 + b3 -> out (fp32, 64 cols)
#pragma unroll
  for (int kk = 0; kk < 4; kk++)
    af[kk] = *(const bf16x8*)(&hbuf[arow][kk * 32 + quad * 8]);
  f32x4 acc3[4];
#pragma unroll
  for (int nt = 0; nt < 4; nt++) acc3[nt] = (f32x4){0,0,0,0};
#pragma unroll
  for (int kk = 0; kk < 4; kk++) {
    int k0 = kk * 32 + quad * 8;
#pragma unroll
    for (int nt = 0; nt < 4; nt++) {
      bf16x8 b8 = *(const bf16x8*)(W3T + (nt * 16 + m) * 128 + k0);
      acc3[nt] = __builtin_amdgcn_mfma_f32_16x16x32_bf16(af[kk], b8, acc3[nt], 0, 0, 0);
    }
  }
#pragma unroll
  for (int nt = 0; nt < 4; nt++) {
    int col = nt * 16 + m;
    float bv = b3[col];
#pragma unroll
    for (int r = 0; r < 4; r++) {
      int node = node_lo + (wv << 4) + quad * 4 + r;
      if (node < n) out[(long)node * 64 + col] = acc3[nt][r] + bv;
    }
  }
}

extern "C" void kernel_launch(void* const* d_in, const int* in_sizes, int n_in,
                              void* d_out, int out_size, void* d_ws, size_t ws_size,
                              hipStream_t stream) {
  const float* x   = (const float*)d_in[0];
  const int*   ei  = (const int*)d_in[1];
  const float* Wl  = (const float*)d_in[2];
  const float* bl  = (const float*)d_in[3];
  const float* Wr  = (const float*)d_in[4];
  const float* br  = (const float*)d_in[5];
  const float* att = (const float*)d_in[6];
  const float* bg  = (const float*)d_in[7];
  const float* W1  = (const float*)d_in[8];
  const float* b1  = (const float*)d_in[9];
  const float* W2  = (const float*)d_in[10];
  const float* b2  = (const float*)d_in[11];
  const float* W3  = (const float*)d_in[12];
  const float* b3  = (const float*)d_in[13];
  float* out = (float*)d_out;

  const int N = in_sizes[0] / DIN;
  const int E = in_sizes[1] / 2;
  const int nbuck = (N + 255) >> 8;

  // workspace layout, every array 256B-aligned
  char* ws = (char*)d_ws;
  size_t off = 0;
  auto alloc = [&](size_t bytes) {
    void* p = ws + off;
    off += (bytes + 255) & ~(size_t)255;
    return p;
  };
  int* ghist     = (int*)alloc(256 * 4);
  int* cum       = (int*)alloc(257 * 4);
  int* cursor    = (int*)alloc(256 * 4);
  unsigned* part = (unsigned*)alloc((size_t)E * 4);
  ushort* xlb    = (ushort*)alloc((size_t)N * DIN * 2);
  ushort* xrb    = (ushort*)alloc((size_t)N * DIN * 2);
  ushort* WlT    = (ushort*)alloc(16384 * 2);
  ushort* WrT    = (ushort*)alloc(16384 * 2);
  ushort* W1T    = (ushort*)alloc(16384 * 2);
  ushort* W2T    = (ushort*)alloc(16384 * 2);
  ushort* W3T    = (ushort*)alloc(8192 * 2);
  (void)ws_size;

  hipMemsetAsync(ghist, 0, 256 * 4, stream);

  int ntile = (E + PTILE - 1) / PTILE;
  cvt_hist_kernel<<<CVT_BLKS + ntile, 256, 0, stream>>>(
      Wl, Wr, W1, W2, W3, WlT, WrT, W1T, W2T, W3T, ei, ghist, E);

  scan_small_kernel<<<1, 256, 0, stream>>>(ghist, cum, cursor);

  int nblk32 = (N + 31) / 32;
  lin_partition_kernel<<<nblk32 + ntile, 256, 0, stream>>>(
      x, WlT, bl, WrT, br, xlb, xrb, N, nblk32, ei, part, cursor, E);

  aggr_mlp_kernel<<<nbuck * 4, 256, 0, stream>>>(
      xlb, xrb, att, bg, part, cum, W1T, b1, W2T, b2, W3T, b3, out, N);
}

// Round 9
// 252.899 us; speedup vs baseline: 1.1625x; 1.1625x over previous
//
#include <hip/hip_runtime.h>
#include <hip/hip_bf16.h>

#define DIN 128
#define NEG_SLOPE 0.2f
#define PTILE 2048        // edges per partition tile
#define FCAP 8192         // fine-kernel LDS edge capacity (mean 4096, sigma~64)
#define CVT_BLKS 289      // blocks of cvt work in the merged cvt+hist kernel

typedef __attribute__((ext_vector_type(8))) short bf16x8;   // 8 bf16 = 4 VGPRs
typedef __attribute__((ext_vector_type(8))) unsigned short u16x8;
typedef __attribute__((ext_vector_type(4))) float f32x4;
typedef __attribute__((ext_vector_type(2))) float f32x2;
typedef __attribute__((ext_vector_type(4))) unsigned int u32x4;

__device__ __forceinline__ ushort f2bf(float f) {
  unsigned u = __float_as_uint(f);
  u += 0x7FFFu + ((u >> 16) & 1u);   // round-to-nearest-even
  return (ushort)(u >> 16);
}
__device__ __forceinline__ float bf2f(ushort u) {
  return __uint_as_float((unsigned)u << 16);
}
// unpack 2 packed bf16 (one dword) -> f32x2 {elem0, elem1}
__device__ __forceinline__ f32x2 bfpair(unsigned u) {
  f32x2 r;
  r.x = __uint_as_float(u << 16);
  r.y = __uint_as_float(u & 0xFFFF0000u);
  return r;
}

// ---------------------------------------------------------------------------
// merged prep: blocks [0,CVT_BLKS) convert weights -> bf16 transposed;
// blocks [CVT_BLKS,...) build the 256-bucket dst histogram (bucket=dst>>8).
// ghist zeroed by hipMemsetAsync before this kernel.
// ---------------------------------------------------------------------------
__global__ __launch_bounds__(256) void cvt_hist_kernel(
    const float* __restrict__ Wl, const float* __restrict__ Wr,
    const float* __restrict__ W1, const float* __restrict__ W2,
    const float* __restrict__ W3,
    ushort* __restrict__ WlT, ushort* __restrict__ WrT,
    ushort* __restrict__ W1T, ushort* __restrict__ W2T,
    ushort* __restrict__ W3T,
    const int* __restrict__ ei, int* __restrict__ ghist, int E) {
  if (blockIdx.x < CVT_BLKS) {
    int i = blockIdx.x * 256 + threadIdx.x;
    if (i < 16384) {
      int k = i >> 7, c = i & 127; WlT[c * 128 + k] = f2bf(Wl[i]);
    } else if (i < 32768) {
      int j = i - 16384; int k = j >> 7, c = j & 127; WrT[c * 128 + k] = f2bf(Wr[j]);
    } else if (i < 49152) {
      int j = i - 32768; int k = j >> 7, c = j & 127; W1T[c * 128 + k] = f2bf(W1[j]);
    } else if (i < 65536) {
      int j = i - 49152; int k = j >> 7, c = j & 127; W2T[c * 128 + k] = f2bf(W2[j]);
    } else if (i < 73728) {
      int j = i - 65536; int k = j >> 6, c = j & 63; W3T[c * 128 + k] = f2bf(W3[j]);
    }
  } else {
    __shared__ int h[256];
    h[threadIdx.x] = 0;
    __syncthreads();
    int tile = blockIdx.x - CVT_BLKS;
    for (int e = tile * PTILE + threadIdx.x;
         e < min(E, (tile + 1) * PTILE); e += 256)
      atomicAdd(&h[ei[E + e] >> 8], 1);
    __syncthreads();
    if (h[threadIdx.x] > 0) atomicAdd(&ghist[threadIdx.x], h[threadIdx.x]);
  }
}

// 1 block: exclusive scan of ghist[256] -> cum[257]; cursor[b] = cum[b].
__global__ __launch_bounds__(256) void scan_small_kernel(
    const int* __restrict__ ghist, int* __restrict__ cum,
    int* __restrict__ cursor) {
  __shared__ int sh[256];
  int tid = threadIdx.x;
  int v = ghist[tid];
  sh[tid] = v;
  __syncthreads();
  for (int d = 1; d < 256; d <<= 1) {
    int t = (tid >= d) ? sh[tid - d] : 0;
    __syncthreads();
    sh[tid] += t;
    __syncthreads();
  }
  int exc = sh[tid] - v;
  cum[tid] = exc;
  cursor[tid] = exc;
  if (tid == 255) cum[256] = sh[255];
}

// ---------------------------------------------------------------------------
// MEGA kernel: blocks [0,nblk_lin) run the lin_lr MFMA GEMM; the rest run
// the partition pass (independent work, overlapped on one dispatch).
// ---------------------------------------------------------------------------
__global__ __launch_bounds__(256) void lin_partition_kernel(
    const float* __restrict__ x,
    const ushort* __restrict__ WlT, const float* __restrict__ bl,
    const ushort* __restrict__ WrT, const float* __restrict__ br,
    ushort* __restrict__ xl, ushort* __restrict__ xr, int n, int nblk_lin,
    const int* __restrict__ ei, unsigned* __restrict__ part,
    int* __restrict__ cursor, int E) {
  if ((int)blockIdx.x < nblk_lin) {
    // ---- lin_lr: xl = x@Wl+bl ; xr = x@Wr+br (bf16 out) ----
    const int tid = threadIdx.x;
    const int wv = tid >> 6, lane = tid & 63;
    const int m = lane & 15, quad = lane >> 4;
    const int colbase = (wv & 1) * 64;
    const int nodew = blockIdx.x * 32 + (wv >> 1) * 16;
    int arow = nodew + m; if (arow >= n) arow = n - 1;
    f32x4 accl[4], accr[4];
#pragma unroll
    for (int nt = 0; nt < 4; nt++) { accl[nt] = (f32x4){0,0,0,0}; accr[nt] = (f32x4){0,0,0,0}; }
#pragma unroll
    for (int kk = 0; kk < 4; kk++) {
      int k0 = kk * 32 + quad * 8;
      const float4* xp = (const float4*)(x + (long)arow * 128 + k0);
      float4 x0 = xp[0], x1 = xp[1];
      bf16x8 af;
      af[0] = (short)f2bf(x0.x); af[1] = (short)f2bf(x0.y);
      af[2] = (short)f2bf(x0.z); af[3] = (short)f2bf(x0.w);
      af[4] = (short)f2bf(x1.x); af[5] = (short)f2bf(x1.y);
      af[6] = (short)f2bf(x1.z); af[7] = (short)f2bf(x1.w);
#pragma unroll
      for (int nt = 0; nt < 4; nt++) {
        int brow = colbase + nt * 16 + m;
        bf16x8 bl8 = *(const bf16x8*)(WlT + brow * 128 + k0);
        bf16x8 br8 = *(const bf16x8*)(WrT + brow * 128 + k0);
        accl[nt] = __builtin_amdgcn_mfma_f32_16x16x32_bf16(af, bl8, accl[nt], 0, 0, 0);
        accr[nt] = __builtin_amdgcn_mfma_f32_16x16x32_bf16(af, br8, accr[nt], 0, 0, 0);
      }
    }
#pragma unroll
    for (int nt = 0; nt < 4; nt++) {
      int col = colbase + nt * 16 + m;
      float vbl = bl[col], vbr = br[col];
#pragma unroll
      for (int r = 0; r < 4; r++) {
        int node = nodew + quad * 4 + r;
        if (node < n) {
          xl[(long)node * 128 + col] = f2bf(accl[nt][r] + vbl);
          xr[(long)node * 128 + col] = f2bf(accr[nt][r] + vbr);
        }
      }
    }
  } else {
    // ---- partition: tile -> LDS bucket-grouped reorder -> dense runs ----
    __shared__ int hist[256], pref[256], sexcl[256], curs[256], gbase[256];
    __shared__ unsigned buf[PTILE];
    const int tid = threadIdx.x;
    const int tile0 = ((int)blockIdx.x - nblk_lin) * PTILE;
    const int tcount = min(PTILE, E - tile0);
    hist[tid] = 0;
    __syncthreads();
    unsigned pk[PTILE / 256];
    int cnt = 0;
    for (int i = tid; i < tcount; i += 256) {
      int e = tile0 + i;
      int s = ei[e], d = ei[E + e];
      unsigned p = ((unsigned)d << 16) | (unsigned)s;
      pk[cnt++] = p;
      atomicAdd(&hist[d >> 8], 1);
    }
    __syncthreads();
    int v = hist[tid];
    pref[tid] = v;
    __syncthreads();
    for (int d = 1; d < 256; d <<= 1) {
      int t = (tid >= d) ? pref[tid - d] : 0;
      __syncthreads();
      pref[tid] += t;
      __syncthreads();
    }
    int exc = pref[tid] - v;
    sexcl[tid] = exc;
    curs[tid] = exc;
    gbase[tid] = (v > 0) ? atomicAdd(&cursor[tid], v) : 0;
    __syncthreads();
    for (int j = 0; j < cnt; j++) {
      int b = pk[j] >> 24;
      int pos = atomicAdd(&curs[b], 1);
      buf[pos] = pk[j];
    }
    __syncthreads();
    for (int i = tid; i < tcount; i += 256) {
      unsigned p = buf[i];
      int b = p >> 24;
      part[gbase[b] + (i - sexcl[b])] = p;
    }
  }
}

// per-bucket: node hist + scan -> offsets; LDS reorder -> coalesced ssrc
// (ushort: src < 65536). 512 threads.
__global__ __launch_bounds__(512) void fine_kernel(
    const unsigned* __restrict__ part, const int* __restrict__ cum,
    int* __restrict__ offsets, ushort* __restrict__ ssrc,
    int N, int E, int nbuck) {
  __shared__ int hist[256], pref[256], curs[256];
  __shared__ unsigned buf[FCAP], buf2[FCAP];
  const int tid = threadIdx.x;
  const int b = blockIdx.x;
  const int seg0 = cum[b];
  const int len = min(cum[b + 1] - seg0, FCAP);
  if (tid < 256) hist[tid] = 0;
  __syncthreads();
  for (int i = tid; i < len; i += 512) {
    unsigned p = part[seg0 + i];
    buf[i] = p;
    atomicAdd(&hist[(p >> 16) & 255], 1);
  }
  __syncthreads();
  int v = (tid < 256) ? hist[tid] : 0;
  if (tid < 256) pref[tid] = v;
  __syncthreads();
  for (int d = 1; d < 256; d <<= 1) {
    int t = (tid >= d && tid < 256) ? pref[tid - d] : 0;
    __syncthreads();
    if (tid < 256) pref[tid] += t;
    __syncthreads();
  }
  if (tid < 256) {
    int exc = pref[tid] - v;
    curs[tid] = exc;
    int node = b * 256 + tid;
    if (node < N) offsets[node] = seg0 + exc;
  }
  if (b == nbuck - 1 && tid == 0) offsets[N] = E;
  __syncthreads();
  for (int i = tid; i < len; i += 512) {
    unsigned p = buf[i];
    int pos = atomicAdd(&curs[(p >> 16) & 255], 1);
    buf2[pos] = p;
  }
  __syncthreads();
  for (int i = tid; i < len; i += 512)
    ssrc[seg0 + i] = (ushort)(buf2[i] & 0xFFFFu);
}

// ---------------------------------------------------------------------------
// Fused per-node GATv2: one wave per dst node; 16 lanes/edge, 4 edge
// subgroups, 4-way slot unroll (16 edges in flight per iteration — avg
// degree is 16, so most nodes do ONE iteration with 4 independent gathers
// per lane: the memory-level parallelism R7 lacked). Packed f32x2 math,
// no max-tracking (scores bounded << 88). ssrc is ushort.
// ---------------------------------------------------------------------------
__global__ __launch_bounds__(256) void node_aggr_kernel(
    const ushort* __restrict__ xl, const ushort* __restrict__ xr,
    const float* __restrict__ att, const float* __restrict__ bg,
    const int* __restrict__ offsets, const ushort* __restrict__ ssrc,
    ushort* __restrict__ h, int n) {
  int wave = (int)((blockIdx.x * (long)blockDim.x + threadIdx.x) >> 6);
  int lane = threadIdx.x & 63;
  if (wave >= n) return;
  const int node = wave;
  const int eg = lane >> 4, sl = lane & 15;
  f32x2 av2[4], r2[4], acc2[4];
  {
    const float4* ap = (const float4*)(att + sl * 8);
    float4 a0 = ap[0], a1 = ap[1];
    av2[0] = (f32x2){a0.x, a0.y}; av2[1] = (f32x2){a0.z, a0.w};
    av2[2] = (f32x2){a1.x, a1.y}; av2[3] = (f32x2){a1.z, a1.w};
  }
  const ushort* xls = xl + sl * 8;
  u32x4 rv = *(const u32x4*)(xr + (long)node * 128 + sl * 8);
  u32x4 lv = *(const u32x4*)(xls + (long)node * 128);
  float denom;
  {
    f32x2 t2 = {0.f, 0.f};
    f32x2 l2[4];
#pragma unroll
    for (int jp = 0; jp < 4; jp++) {
      r2[jp] = bfpair(rv[jp]);
      l2[jp] = bfpair(lv[jp]);
      f32x2 v = l2[jp] + r2[jp];
      t2 += __builtin_elementwise_max(v, NEG_SLOPE * v) * av2[jp];
    }
    float t = t2.x + t2.y;
#pragma unroll
    for (int off = 1; off < 16; off <<= 1) t += __shfl_xor(t, off);
    float es = __expf(t);             // self-loop weight
    denom = (eg == 0) ? es : 0.f;
#pragma unroll
    for (int jp = 0; jp < 4; jp++)
      acc2[jp] = (eg == 0) ? es * l2[jp] : (f32x2){0.f, 0.f};
  }
  const int beg = offsets[node];
  const int end = offsets[node + 1];
  for (int p = beg; p < end; p += 16) {
    int i0 = p + 4 * eg;
    bool v0 = i0 < end, v1 = i0 + 1 < end, v2 = i0 + 2 < end, v3 = i0 + 3 < end;
    int s0 = v0 ? (int)ssrc[i0]     : node;   // clamp: safe in-bounds row
    int s1 = v1 ? (int)ssrc[i0 + 1] : node;
    int s2 = v2 ? (int)ssrc[i0 + 2] : node;
    int s3 = v3 ? (int)ssrc[i0 + 3] : node;
    u32x4 uv0 = *(const u32x4*)(xls + (long)s0 * 128);
    u32x4 uv1 = *(const u32x4*)(xls + (long)s1 * 128);
    u32x4 uv2 = *(const u32x4*)(xls + (long)s2 * 128);
    u32x4 uv3 = *(const u32x4*)(xls + (long)s3 * 128);
    f32x2 u0[4], u1[4], u2[4], u3[4];
    f32x2 t0 = {0.f, 0.f}, t1 = {0.f, 0.f}, t2 = {0.f, 0.f}, t3 = {0.f, 0.f};
#pragma unroll
    for (int jp = 0; jp < 4; jp++) {
      u0[jp] = bfpair(uv0[jp]);
      u1[jp] = bfpair(uv1[jp]);
      u2[jp] = bfpair(uv2[jp]);
      u3[jp] = bfpair(uv3[jp]);
      f32x2 w0 = u0[jp] + r2[jp];
      f32x2 w1 = u1[jp] + r2[jp];
      f32x2 w2 = u2[jp] + r2[jp];
      f32x2 w3 = u3[jp] + r2[jp];
      t0 += __builtin_elementwise_max(w0, NEG_SLOPE * w0) * av2[jp];
      t1 += __builtin_elementwise_max(w1, NEG_SLOPE * w1) * av2[jp];
      t2 += __builtin_elementwise_max(w2, NEG_SLOPE * w2) * av2[jp];
      t3 += __builtin_elementwise_max(w3, NEG_SLOPE * w3) * av2[jp];
    }
    float a0 = t0.x + t0.y, a1 = t1.x + t1.y;
    float a2 = t2.x + t2.y, a3 = t3.x + t3.y;
#pragma unroll
    for (int off = 1; off < 16; off <<= 1) {
      a0 += __shfl_xor(a0, off);
      a1 += __shfl_xor(a1, off);
      a2 += __shfl_xor(a2, off);
      a3 += __shfl_xor(a3, off);
    }
    float e0 = v0 ? __expf(a0) : 0.f;
    float e1 = v1 ? __expf(a1) : 0.f;
    float e2 = v2 ? __expf(a2) : 0.f;
    float e3 = v3 ? __expf(a3) : 0.f;
    denom += (e0 + e1) + (e2 + e3);
#pragma unroll
    for (int jp = 0; jp < 4; jp++)
      acc2[jp] += (e0 * u0[jp] + e1 * u1[jp]) + (e2 * u2[jp] + e3 * u3[jp]);
  }
  // combine the 4 edge-subgroup replicas
#pragma unroll
  for (int jp = 0; jp < 4; jp++) {
    acc2[jp].x += __shfl_xor(acc2[jp].x, 16);
    acc2[jp].y += __shfl_xor(acc2[jp].y, 16);
    acc2[jp].x += __shfl_xor(acc2[jp].x, 32);
    acc2[jp].y += __shfl_xor(acc2[jp].y, 32);
  }
  denom += __shfl_xor(denom, 16);
  denom += __shfl_xor(denom, 32);
  if (eg == 0) {
    float inv = 1.0f / denom;
    const float4* bp = (const float4*)(bg + sl * 8);
    float4 g0 = bp[0], g1 = bp[1];
    f32x2 gv[4] = {{g0.x, g0.y}, {g0.z, g0.w}, {g1.x, g1.y}, {g1.z, g1.w}};
    u16x8 o;
#pragma unroll
    for (int jp = 0; jp < 4; jp++) {
      f32x2 hv = acc2[jp] * inv + gv[jp];
      o[2 * jp]     = f2bf(hv.x);
      o[2 * jp + 1] = f2bf(hv.y);
    }
    *(u16x8*)(h + (long)node * 128 + sl * 8) = o;
  }
}

// ---------------------------------------------------------------------------
// k5 (MFMA): out = relu(relu(h@W1+b1)@W2+b2)@W3+b3 ; 32 nodes/block, 4 waves.
// ---------------------------------------------------------------------------
#define LDSP 136
__global__ __launch_bounds__(256) void mlp_mfma_kernel(
    const ushort* __restrict__ hb,
    const ushort* __restrict__ W1T, const float* __restrict__ b1,
    const ushort* __restrict__ W2T, const float* __restrict__ b2,
    const ushort* __restrict__ W3T, const float* __restrict__ b3,
    float* __restrict__ out, int n) {
  __shared__ ushort act[32][LDSP];
  const int tid = threadIdx.x;
  const int wv = tid >> 6, lane = tid & 63;
  const int m = lane & 15, quad = lane >> 4;
  const int half = wv & 1, ng = wv >> 1;
  const int colbase = half * 64;
  const int nodew = blockIdx.x * 32 + ng * 16;
  int arow = nodew + m; if (arow >= n) arow = n - 1;
  f32x4 acc[4];
#pragma unroll
  for (int nt = 0; nt < 4; nt++) acc[nt] = (f32x4){0,0,0,0};
#pragma unroll
  for (int kk = 0; kk < 4; kk++) {
    int k0 = kk * 32 + quad * 8;
    bf16x8 af = *(const bf16x8*)(hb + (long)arow * 128 + k0);
#pragma unroll
    for (int nt = 0; nt < 4; nt++) {
      bf16x8 b8 = *(const bf16x8*)(W1T + (colbase + nt * 16 + m) * 128 + k0);
      acc[nt] = __builtin_amdgcn_mfma_f32_16x16x32_bf16(af, b8, acc[nt], 0, 0, 0);
    }
  }
#pragma unroll
  for (int nt = 0; nt < 4; nt++) {
    int col = colbase + nt * 16 + m;
    float b = b1[col];
#pragma unroll
    for (int r = 0; r < 4; r++)
      act[ng * 16 + quad * 4 + r][col] = f2bf(fmaxf(acc[nt][r] + b, 0.f));
  }
  __syncthreads();
#pragma unroll
  for (int nt = 0; nt < 4; nt++) acc[nt] = (f32x4){0,0,0,0};
#pragma unroll
  for (int kk = 0; kk < 4; kk++) {
    int k0 = kk * 32 + quad * 8;
    bf16x8 af = *(const bf16x8*)(&act[ng * 16 + m][k0]);
#pragma unroll
    for (int nt = 0; nt < 4; nt++) {
      bf16x8 b8 = *(const bf16x8*)(W2T + (colbase + nt * 16 + m) * 128 + k0);
      acc[nt] = __builtin_amdgcn_mfma_f32_16x16x32_bf16(af, b8, acc[nt], 0, 0, 0);
    }
  }
  __syncthreads();
#pragma unroll
  for (int nt = 0; nt < 4; nt++) {
    int col = colbase + nt * 16 + m;
    float b = b2[col];
#pragma unroll
    for (int r = 0; r < 4; r++)
      act[ng * 16 + quad * 4 + r][col] = f2bf(fmaxf(acc[nt][r] + b, 0.f));
  }
  __syncthreads();
  f32x4 acc3[2];
#pragma unroll
  for (int nt = 0; nt < 2; nt++) acc3[nt] = (f32x4){0,0,0,0};
#pragma unroll
  for (int kk = 0; kk < 4; kk++) {
    int k0 = kk * 32 + quad * 8;
    bf16x8 af = *(const bf16x8*)(&act[ng * 16 + m][k0]);
#pragma unroll
    for (int nt = 0; nt < 2; nt++) {
      bf16x8 b8 = *(const bf16x8*)(W3T + (half * 32 + nt * 16 + m) * 128 + k0);
      acc3[nt] = __builtin_amdgcn_mfma_f32_16x16x32_bf16(af, b8, acc3[nt], 0, 0, 0);
    }
  }
#pragma unroll
  for (int nt = 0; nt < 2; nt++) {
    int col = half * 32 + nt * 16 + m;
    float b = b3[col];
#pragma unroll
    for (int r = 0; r < 4; r++) {
      int node = nodew + quad * 4 + r;
      if (node < n) out[(long)node * 64 + col] = acc3[nt][r] + b;
    }
  }
}

extern "C" void kernel_launch(void* const* d_in, const int* in_sizes, int n_in,
                              void* d_out, int out_size, void* d_ws, size_t ws_size,
                              hipStream_t stream) {
  const float* x   = (const float*)d_in[0];
  const int*   ei  = (const int*)d_in[1];
  const float* Wl  = (const float*)d_in[2];
  const float* bl  = (const float*)d_in[3];
  const float* Wr  = (const float*)d_in[4];
  const float* br  = (const float*)d_in[5];
  const float* att = (const float*)d_in[6];
  const float* bg  = (const float*)d_in[7];
  const float* W1  = (const float*)d_in[8];
  const float* b1  = (const float*)d_in[9];
  const float* W2  = (const float*)d_in[10];
  const float* b2  = (const float*)d_in[11];
  const float* W3  = (const float*)d_in[12];
  const float* b3  = (const float*)d_in[13];
  float* out = (float*)d_out;

  const int N = in_sizes[0] / DIN;
  const int E = in_sizes[1] / 2;
  const int nbuck = (N + 255) >> 8;

  // workspace layout, every array 256B-aligned (row gathers must not split
  // cachelines)
  char* ws = (char*)d_ws;
  size_t off = 0;
  auto alloc = [&](size_t bytes) {
    void* p = ws + off;
    off += (bytes + 255) & ~(size_t)255;
    return p;
  };
  int* ghist     = (int*)alloc(256 * 4);
  int* cum       = (int*)alloc(257 * 4);
  int* cursor    = (int*)alloc(256 * 4);
  int* offsets   = (int*)alloc(((size_t)N + 4) * 4);
  unsigned* part = (unsigned*)alloc((size_t)E * 4);
  ushort* ssrc   = (ushort*)alloc(((size_t)E + 16) * 2);
  ushort* xlb    = (ushort*)alloc((size_t)N * DIN * 2);
  ushort* xrb    = (ushort*)alloc((size_t)N * DIN * 2);
  ushort* hbf    = (ushort*)alloc((size_t)N * DIN * 2);
  ushort* WlT    = (ushort*)alloc(16384 * 2);
  ushort* WrT    = (ushort*)alloc(16384 * 2);
  ushort* W1T    = (ushort*)alloc(16384 * 2);
  ushort* W2T    = (ushort*)alloc(16384 * 2);
  ushort* W3T    = (ushort*)alloc(8192 * 2);
  (void)ws_size;

  hipMemsetAsync(ghist, 0, 256 * 4, stream);

  int ntile = (E + PTILE - 1) / PTILE;
  cvt_hist_kernel<<<CVT_BLKS + ntile, 256, 0, stream>>>(
      Wl, Wr, W1, W2, W3, WlT, WrT, W1T, W2T, W3T, ei, ghist, E);

  scan_small_kernel<<<1, 256, 0, stream>>>(ghist, cum, cursor);

  int nblk32 = (N + 31) / 32;
  lin_partition_kernel<<<nblk32 + ntile, 256, 0, stream>>>(
      x, WlT, bl, WrT, br, xlb, xrb, N, nblk32, ei, part, cursor, E);

  fine_kernel<<<nbuck, 512, 0, stream>>>(part, cum, offsets, ssrc, N, E, nbuck);

  int nwblk = (N + 3) / 4;  // 4 waves (nodes) per 256-thread block
  node_aggr_kernel<<<nwblk, 256, 0, stream>>>(xlb, xrb, att, bg,
                                              offsets, ssrc, hbf, N);

  mlp_mfma_kernel<<<nblk32, 256, 0, stream>>>(hbf, W1T, b1, W2T, b2,
                                              W3T, b3, out, N);
}

// Round 10
// 248.779 us; speedup vs baseline: 1.1818x; 1.0166x over previous
//
#include <hip/hip_runtime.h>
#include <hip/hip_bf16.h>

#define DIN 128
#define NEG_SLOPE 0.2f
#define PTILE 2048        // edges per partition tile
#define FCAP 8192         // fine-kernel LDS edge capacity (mean 4096, sigma~64)
#define CVT_BLKS 289      // blocks of cvt work in the merged cvt+hist kernel

typedef __attribute__((ext_vector_type(8))) short bf16x8;   // 8 bf16 = 4 VGPRs
typedef __attribute__((ext_vector_type(8))) unsigned short u16x8;
typedef __attribute__((ext_vector_type(4))) float f32x4;
typedef __attribute__((ext_vector_type(2))) float f32x2;
typedef __attribute__((ext_vector_type(4))) unsigned int u32x4;

__device__ __forceinline__ ushort f2bf(float f) {
  unsigned u = __float_as_uint(f);
  u += 0x7FFFu + ((u >> 16) & 1u);   // round-to-nearest-even
  return (ushort)(u >> 16);
}
__device__ __forceinline__ float bf2f(ushort u) {
  return __uint_as_float((unsigned)u << 16);
}
// unpack 2 packed bf16 (one dword) -> f32x2 {elem0, elem1}
__device__ __forceinline__ f32x2 bfpair(unsigned u) {
  f32x2 r;
  r.x = __uint_as_float(u << 16);
  r.y = __uint_as_float(u & 0xFFFF0000u);
  return r;
}

// ---------------------------------------------------------------------------
// merged prep: blocks [0,CVT_BLKS) convert weights -> bf16 transposed;
// blocks [CVT_BLKS,...) build the 256-bucket dst histogram (bucket=dst>>8).
// ghist zeroed by hipMemsetAsync before this kernel.
// ---------------------------------------------------------------------------
__global__ __launch_bounds__(256) void cvt_hist_kernel(
    const float* __restrict__ Wl, const float* __restrict__ Wr,
    const float* __restrict__ W1, const float* __restrict__ W2,
    const float* __restrict__ W3,
    ushort* __restrict__ WlT, ushort* __restrict__ WrT,
    ushort* __restrict__ W1T, ushort* __restrict__ W2T,
    ushort* __restrict__ W3T,
    const int* __restrict__ ei, int* __restrict__ ghist, int E) {
  if (blockIdx.x < CVT_BLKS) {
    int i = blockIdx.x * 256 + threadIdx.x;
    if (i < 16384) {
      int k = i >> 7, c = i & 127; WlT[c * 128 + k] = f2bf(Wl[i]);
    } else if (i < 32768) {
      int j = i - 16384; int k = j >> 7, c = j & 127; WrT[c * 128 + k] = f2bf(Wr[j]);
    } else if (i < 49152) {
      int j = i - 32768; int k = j >> 7, c = j & 127; W1T[c * 128 + k] = f2bf(W1[j]);
    } else if (i < 65536) {
      int j = i - 49152; int k = j >> 7, c = j & 127; W2T[c * 128 + k] = f2bf(W2[j]);
    } else if (i < 73728) {
      int j = i - 65536; int k = j >> 6, c = j & 63; W3T[c * 128 + k] = f2bf(W3[j]);
    }
  } else {
    __shared__ int h[256];
    h[threadIdx.x] = 0;
    __syncthreads();
    int tile = blockIdx.x - CVT_BLKS;
    for (int e = tile * PTILE + threadIdx.x;
         e < min(E, (tile + 1) * PTILE); e += 256)
      atomicAdd(&h[ei[E + e] >> 8], 1);
    __syncthreads();
    if (h[threadIdx.x] > 0) atomicAdd(&ghist[threadIdx.x], h[threadIdx.x]);
  }
}

// 1 block: exclusive scan of ghist[256] -> cum[257]; cursor[b] = cum[b].
__global__ __launch_bounds__(256) void scan_small_kernel(
    const int* __restrict__ ghist, int* __restrict__ cum,
    int* __restrict__ cursor) {
  __shared__ int sh[256];
  int tid = threadIdx.x;
  int v = ghist[tid];
  sh[tid] = v;
  __syncthreads();
  for (int d = 1; d < 256; d <<= 1) {
    int t = (tid >= d) ? sh[tid - d] : 0;
    __syncthreads();
    sh[tid] += t;
    __syncthreads();
  }
  int exc = sh[tid] - v;
  cum[tid] = exc;
  cursor[tid] = exc;
  if (tid == 255) cum[256] = sh[255];
}

// ---------------------------------------------------------------------------
// MEGA kernel: blocks [0,nblk_lin) run the lin_lr MFMA GEMM; the rest run
// the partition pass (independent work, overlapped on one dispatch).
// ---------------------------------------------------------------------------
__global__ __launch_bounds__(256) void lin_partition_kernel(
    const float* __restrict__ x,
    const ushort* __restrict__ WlT, const float* __restrict__ bl,
    const ushort* __restrict__ WrT, const float* __restrict__ br,
    ushort* __restrict__ xl, ushort* __restrict__ xr, int n, int nblk_lin,
    const int* __restrict__ ei, unsigned* __restrict__ part,
    int* __restrict__ cursor, int E) {
  if ((int)blockIdx.x < nblk_lin) {
    // ---- lin_lr: xl = x@Wl+bl ; xr = x@Wr+br (bf16 out) ----
    const int tid = threadIdx.x;
    const int wv = tid >> 6, lane = tid & 63;
    const int m = lane & 15, quad = lane >> 4;
    const int colbase = (wv & 1) * 64;
    const int nodew = blockIdx.x * 32 + (wv >> 1) * 16;
    int arow = nodew + m; if (arow >= n) arow = n - 1;
    f32x4 accl[4], accr[4];
#pragma unroll
    for (int nt = 0; nt < 4; nt++) { accl[nt] = (f32x4){0,0,0,0}; accr[nt] = (f32x4){0,0,0,0}; }
#pragma unroll
    for (int kk = 0; kk < 4; kk++) {
      int k0 = kk * 32 + quad * 8;
      const float4* xp = (const float4*)(x + (long)arow * 128 + k0);
      float4 x0 = xp[0], x1 = xp[1];
      bf16x8 af;
      af[0] = (short)f2bf(x0.x); af[1] = (short)f2bf(x0.y);
      af[2] = (short)f2bf(x0.z); af[3] = (short)f2bf(x0.w);
      af[4] = (short)f2bf(x1.x); af[5] = (short)f2bf(x1.y);
      af[6] = (short)f2bf(x1.z); af[7] = (short)f2bf(x1.w);
#pragma unroll
      for (int nt = 0; nt < 4; nt++) {
        int brow = colbase + nt * 16 + m;
        bf16x8 bl8 = *(const bf16x8*)(WlT + brow * 128 + k0);
        bf16x8 br8 = *(const bf16x8*)(WrT + brow * 128 + k0);
        accl[nt] = __builtin_amdgcn_mfma_f32_16x16x32_bf16(af, bl8, accl[nt], 0, 0, 0);
        accr[nt] = __builtin_amdgcn_mfma_f32_16x16x32_bf16(af, br8, accr[nt], 0, 0, 0);
      }
    }
#pragma unroll
    for (int nt = 0; nt < 4; nt++) {
      int col = colbase + nt * 16 + m;
      float vbl = bl[col], vbr = br[col];
#pragma unroll
      for (int r = 0; r < 4; r++) {
        int node = nodew + quad * 4 + r;
        if (node < n) {
          xl[(long)node * 128 + col] = f2bf(accl[nt][r] + vbl);
          xr[(long)node * 128 + col] = f2bf(accr[nt][r] + vbr);
        }
      }
    }
  } else {
    // ---- partition: tile -> LDS bucket-grouped reorder -> dense runs ----
    __shared__ int hist[256], pref[256], sexcl[256], curs[256], gbase[256];
    __shared__ unsigned buf[PTILE];
    const int tid = threadIdx.x;
    const int tile0 = ((int)blockIdx.x - nblk_lin) * PTILE;
    const int tcount = min(PTILE, E - tile0);
    hist[tid] = 0;
    __syncthreads();
    unsigned pk[PTILE / 256];
    int cnt = 0;
    for (int i = tid; i < tcount; i += 256) {
      int e = tile0 + i;
      int s = ei[e], d = ei[E + e];
      unsigned p = ((unsigned)d << 16) | (unsigned)s;
      pk[cnt++] = p;
      atomicAdd(&hist[d >> 8], 1);
    }
    __syncthreads();
    int v = hist[tid];
    pref[tid] = v;
    __syncthreads();
    for (int d = 1; d < 256; d <<= 1) {
      int t = (tid >= d) ? pref[tid - d] : 0;
      __syncthreads();
      pref[tid] += t;
      __syncthreads();
    }
    int exc = pref[tid] - v;
    sexcl[tid] = exc;
    curs[tid] = exc;
    gbase[tid] = (v > 0) ? atomicAdd(&cursor[tid], v) : 0;
    __syncthreads();
    for (int j = 0; j < cnt; j++) {
      int b = pk[j] >> 24;
      int pos = atomicAdd(&curs[b], 1);
      buf[pos] = pk[j];
    }
    __syncthreads();
    for (int i = tid; i < tcount; i += 256) {
      unsigned p = buf[i];
      int b = p >> 24;
      part[gbase[b] + (i - sexcl[b])] = p;
    }
  }
}

// per-bucket: node hist + scan -> offsets; LDS reorder -> coalesced ssrc
// (ushort: src < 65536). 512 threads.
__global__ __launch_bounds__(512) void fine_kernel(
    const unsigned* __restrict__ part, const int* __restrict__ cum,
    int* __restrict__ offsets, ushort* __restrict__ ssrc,
    int N, int E, int nbuck) {
  __shared__ int hist[256], pref[256], curs[256];
  __shared__ unsigned buf[FCAP], buf2[FCAP];
  const int tid = threadIdx.x;
  const int b = blockIdx.x;
  const int seg0 = cum[b];
  const int len = min(cum[b + 1] - seg0, FCAP);
  if (tid < 256) hist[tid] = 0;
  __syncthreads();
  for (int i = tid; i < len; i += 512) {
    unsigned p = part[seg0 + i];
    buf[i] = p;
    atomicAdd(&hist[(p >> 16) & 255], 1);
  }
  __syncthreads();
  int v = (tid < 256) ? hist[tid] : 0;
  if (tid < 256) pref[tid] = v;
  __syncthreads();
  for (int d = 1; d < 256; d <<= 1) {
    int t = (tid >= d && tid < 256) ? pref[tid - d] : 0;
    __syncthreads();
    if (tid < 256) pref[tid] += t;
    __syncthreads();
  }
  if (tid < 256) {
    int exc = pref[tid] - v;
    curs[tid] = exc;
    int node = b * 256 + tid;
    if (node < N) offsets[node] = seg0 + exc;
  }
  if (b == nbuck - 1 && tid == 0) offsets[N] = E;
  __syncthreads();
  for (int i = tid; i < len; i += 512) {
    unsigned p = buf[i];
    int pos = atomicAdd(&curs[(p >> 16) & 255], 1);
    buf2[pos] = p;
  }
  __syncthreads();
  for (int i = tid; i < len; i += 512)
    ssrc[seg0 + i] = (ushort)(buf2[i] & 0xFFFFu);
}

// ---------------------------------------------------------------------------
// Fused per-node GATv2: one wave per dst node; 16 lanes/edge, 4 edge
// subgroups, 8 edge-slots per iteration (R7's slot-efficient shape) with a
// SOFTWARE PIPELINE: indices 2 iterations deep, rows 1 deep. At iteration k
// the body issues rows(k+1) (indices already resident) and idx(k+2), then
// computes k — 4 row-gathers in flight per lane with zero wasted slots.
// Packed f32x2 math, no max-tracking (scores bounded << 88). ssrc ushort.
// ---------------------------------------------------------------------------
__global__ __launch_bounds__(256) void node_aggr_kernel(
    const ushort* __restrict__ xl, const ushort* __restrict__ xr,
    const float* __restrict__ att, const float* __restrict__ bg,
    const int* __restrict__ offsets, const ushort* __restrict__ ssrc,
    ushort* __restrict__ h, int n) {
  int wave = (int)((blockIdx.x * (long)blockDim.x + threadIdx.x) >> 6);
  int lane = threadIdx.x & 63;
  if (wave >= n) return;
  const int node = wave;
  const int eg = lane >> 4, sl = lane & 15;
  f32x2 av2[4], r2[4], acc2[4];
  {
    const float4* ap = (const float4*)(att + sl * 8);
    float4 a0 = ap[0], a1 = ap[1];
    av2[0] = (f32x2){a0.x, a0.y}; av2[1] = (f32x2){a0.z, a0.w};
    av2[2] = (f32x2){a1.x, a1.y}; av2[3] = (f32x2){a1.z, a1.w};
  }
  const ushort* xls = xl + sl * 8;
  u32x4 rv = *(const u32x4*)(xr + (long)node * 128 + sl * 8);
  u32x4 lv = *(const u32x4*)(xls + (long)node * 128);
  const int beg = offsets[node];
  const int end = offsets[node + 1];

  // pipeline preamble: idx+rows for iter0, idx for iter1
  int ia = beg + 2 * eg;
  bool va = ia < end, vb = ia + 1 < end;
  int sa = va ? (int)ssrc[ia] : node;       // clamp: safe in-bounds row
  int sb = vb ? (int)ssrc[ia + 1] : node;
  u32x4 uva = *(const u32x4*)(xls + (long)sa * 128);
  u32x4 uvb = *(const u32x4*)(xls + (long)sb * 128);
  int ian = beg + 8 + 2 * eg;
  bool van = ian < end, vbn = ian + 1 < end;
  int san = van ? (int)ssrc[ian] : node;
  int sbn = vbn ? (int)ssrc[ian + 1] : node;

  float denom;
  {
    f32x2 t2 = {0.f, 0.f};
    f32x2 l2[4];
#pragma unroll
    for (int jp = 0; jp < 4; jp++) {
      r2[jp] = bfpair(rv[jp]);
      l2[jp] = bfpair(lv[jp]);
      f32x2 v = l2[jp] + r2[jp];
      t2 += __builtin_elementwise_max(v, NEG_SLOPE * v) * av2[jp];
    }
    float t = t2.x + t2.y;
#pragma unroll
    for (int off = 1; off < 16; off <<= 1) t += __shfl_xor(t, off);
    float es = __expf(t);             // self-loop weight
    denom = (eg == 0) ? es : 0.f;
#pragma unroll
    for (int jp = 0; jp < 4; jp++)
      acc2[jp] = (eg == 0) ? es * l2[jp] : (f32x2){0.f, 0.f};
  }

  for (int p = beg; p < end; p += 8) {
    // issue rows for iter k+1 (indices already resident — no idx->row chain)
    u32x4 uvan = *(const u32x4*)(xls + (long)san * 128);
    u32x4 uvbn = *(const u32x4*)(xls + (long)sbn * 128);
    // issue idx for iter k+2
    int ia2 = p + 16 + 2 * eg;
    bool va2 = ia2 < end, vb2 = ia2 + 1 < end;
    int sa2 = va2 ? (int)ssrc[ia2] : node;
    int sb2 = vb2 ? (int)ssrc[ia2 + 1] : node;
    // compute iter k
    f32x2 ua2[4], ub2[4];
    f32x2 ta2 = {0.f, 0.f}, tb2 = {0.f, 0.f};
#pragma unroll
    for (int jp = 0; jp < 4; jp++) {
      ua2[jp] = bfpair(uva[jp]);
      ub2[jp] = bfpair(uvb[jp]);
      f32x2 wa = ua2[jp] + r2[jp];
      f32x2 wb = ub2[jp] + r2[jp];
      ta2 += __builtin_elementwise_max(wa, NEG_SLOPE * wa) * av2[jp];
      tb2 += __builtin_elementwise_max(wb, NEG_SLOPE * wb) * av2[jp];
    }
    float ta = ta2.x + ta2.y, tb = tb2.x + tb2.y;
#pragma unroll
    for (int off = 1; off < 16; off <<= 1) {
      ta += __shfl_xor(ta, off);
      tb += __shfl_xor(tb, off);
    }
    float ea = va ? __expf(ta) : 0.f;
    float eb = vb ? __expf(tb) : 0.f;
    denom += ea + eb;
#pragma unroll
    for (int jp = 0; jp < 4; jp++)
      acc2[jp] += ea * ua2[jp] + eb * ub2[jp];
    // rotate pipeline
    uva = uvan; uvb = uvbn;
    va = van;   vb = vbn;
    san = sa2;  sbn = sb2;
    van = va2;  vbn = vb2;
  }
  // combine the 4 edge-subgroup replicas
#pragma unroll
  for (int jp = 0; jp < 4; jp++) {
    acc2[jp].x += __shfl_xor(acc2[jp].x, 16);
    acc2[jp].y += __shfl_xor(acc2[jp].y, 16);
    acc2[jp].x += __shfl_xor(acc2[jp].x, 32);
    acc2[jp].y += __shfl_xor(acc2[jp].y, 32);
  }
  denom += __shfl_xor(denom, 16);
  denom += __shfl_xor(denom, 32);
  if (eg == 0) {
    float inv = 1.0f / denom;
    const float4* bp = (const float4*)(bg + sl * 8);
    float4 g0 = bp[0], g1 = bp[1];
    f32x2 gv[4] = {{g0.x, g0.y}, {g0.z, g0.w}, {g1.x, g1.y}, {g1.z, g1.w}};
    u16x8 o;
#pragma unroll
    for (int jp = 0; jp < 4; jp++) {
      f32x2 hv = acc2[jp] * inv + gv[jp];
      o[2 * jp]     = f2bf(hv.x);
      o[2 * jp + 1] = f2bf(hv.y);
    }
    *(u16x8*)(h + (long)node * 128 + sl * 8) = o;
  }
}

// ---------------------------------------------------------------------------
// k5 (MFMA): out = relu(relu(h@W1+b1)@W2+b2)@W3+b3 ; 32 nodes/block, 4 waves.
// ---------------------------------------------------------------------------
#define LDSP 136
__global__ __launch_bounds__(256) void mlp_mfma_kernel(
    const ushort* __restrict__ hb,
    const ushort* __restrict__ W1T, const float* __restrict__ b1,
    const ushort* __restrict__ W2T, const float* __restrict__ b2,
    const ushort* __restrict__ W3T, const float* __restrict__ b3,
    float* __restrict__ out, int n) {
  __shared__ ushort act[32][LDSP];
  const int tid = threadIdx.x;
  const int wv = tid >> 6, lane = tid & 63;
  const int m = lane & 15, quad = lane >> 4;
  const int half = wv & 1, ng = wv >> 1;
  const int colbase = half * 64;
  const int nodew = blockIdx.x * 32 + ng * 16;
  int arow = nodew + m; if (arow >= n) arow = n - 1;
  f32x4 acc[4];
#pragma unroll
  for (int nt = 0; nt < 4; nt++) acc[nt] = (f32x4){0,0,0,0};
#pragma unroll
  for (int kk = 0; kk < 4; kk++) {
    int k0 = kk * 32 + quad * 8;
    bf16x8 af = *(const bf16x8*)(hb + (long)arow * 128 + k0);
#pragma unroll
    for (int nt = 0; nt < 4; nt++) {
      bf16x8 b8 = *(const bf16x8*)(W1T + (colbase + nt * 16 + m) * 128 + k0);
      acc[nt] = __builtin_amdgcn_mfma_f32_16x16x32_bf16(af, b8, acc[nt], 0, 0, 0);
    }
  }
#pragma unroll
  for (int nt = 0; nt < 4; nt++) {
    int col = colbase + nt * 16 + m;
    float b = b1[col];
#pragma unroll
    for (int r = 0; r < 4; r++)
      act[ng * 16 + quad * 4 + r][col] = f2bf(fmaxf(acc[nt][r] + b, 0.f));
  }
  __syncthreads();
#pragma unroll
  for (int nt = 0; nt < 4; nt++) acc[nt] = (f32x4){0,0,0,0};
#pragma unroll
  for (int kk = 0; kk < 4; kk++) {
    int k0 = kk * 32 + quad * 8;
    bf16x8 af = *(const bf16x8*)(&act[ng * 16 + m][k0]);
#pragma unroll
    for (int nt = 0; nt < 4; nt++) {
      bf16x8 b8 = *(const bf16x8*)(W2T + (colbase + nt * 16 + m) * 128 + k0);
      acc[nt] = __builtin_amdgcn_mfma_f32_16x16x32_bf16(af, b8, acc[nt], 0, 0, 0);
    }
  }
  __syncthreads();
#pragma unroll
  for (int nt = 0; nt < 4; nt++) {
    int col = colbase + nt * 16 + m;
    float b = b2[col];
#pragma unroll
    for (int r = 0; r < 4; r++)
      act[ng * 16 + quad * 4 + r][col] = f2bf(fmaxf(acc[nt][r] + b, 0.f));
  }
  __syncthreads();
  f32x4 acc3[2];
#pragma unroll
  for (int nt = 0; nt < 2; nt++) acc3[nt] = (f32x4){0,0,0,0};
#pragma unroll
  for (int kk = 0; kk < 4; kk++) {
    int k0 = kk * 32 + quad * 8;
    bf16x8 af = *(const bf16x8*)(&act[ng * 16 + m][k0]);
#pragma unroll
    for (int nt = 0; nt < 2; nt++) {
      bf16x8 b8 = *(const bf16x8*)(W3T + (half * 32 + nt * 16 + m) * 128 + k0);
      acc3[nt] = __builtin_amdgcn_mfma_f32_16x16x32_bf16(af, b8, acc3[nt], 0, 0, 0);
    }
  }
#pragma unroll
  for (int nt = 0; nt < 2; nt++) {
    int col = half * 32 + nt * 16 + m;
    float b = b3[col];
#pragma unroll
    for (int r = 0; r < 4; r++) {
      int node = nodew + quad * 4 + r;
      if (node < n) out[(long)node * 64 + col] = acc3[nt][r] + b;
    }
  }
}

extern "C" void kernel_launch(void* const* d_in, const int* in_sizes, int n_in,
                              void* d_out, int out_size, void* d_ws, size_t ws_size,
                              hipStream_t stream) {
  const float* x   = (const float*)d_in[0];
  const int*   ei  = (const int*)d_in[1];
  const float* Wl  = (const float*)d_in[2];
  const float* bl  = (const float*)d_in[3];
  const float* Wr  = (const float*)d_in[4];
  const float* br  = (const float*)d_in[5];
  const float* att = (const float*)d_in[6];
  const float* bg  = (const float*)d_in[7];
  const float* W1  = (const float*)d_in[8];
  const float* b1  = (const float*)d_in[9];
  const float* W2  = (const float*)d_in[10];
  const float* b2  = (const float*)d_in[11];
  const float* W3  = (const float*)d_in[12];
  const float* b3  = (const float*)d_in[13];
  float* out = (float*)d_out;

  const int N = in_sizes[0] / DIN;
  const int E = in_sizes[1] / 2;
  const int nbuck = (N + 255) >> 8;

  // workspace layout, every array 256B-aligned (row gathers must not split
  // cachelines)
  char* ws = (char*)d_ws;
  size_t off = 0;
  auto alloc = [&](size_t bytes) {
    void* p = ws + off;
    off += (bytes + 255) & ~(size_t)255;
    return p;
  };
  int* ghist     = (int*)alloc(256 * 4);
  int* cum       = (int*)alloc(257 * 4);
  int* cursor    = (int*)alloc(256 * 4);
  int* offsets   = (int*)alloc(((size_t)N + 4) * 4);
  unsigned* part = (unsigned*)alloc((size_t)E * 4);
  ushort* ssrc   = (ushort*)alloc(((size_t)E + 32) * 2);
  ushort* xlb    = (ushort*)alloc((size_t)N * DIN * 2);
  ushort* xrb    = (ushort*)alloc((size_t)N * DIN * 2);
  ushort* hbf    = (ushort*)alloc((size_t)N * DIN * 2);
  ushort* WlT    = (ushort*)alloc(16384 * 2);
  ushort* WrT    = (ushort*)alloc(16384 * 2);
  ushort* W1T    = (ushort*)alloc(16384 * 2);
  ushort* W2T    = (ushort*)alloc(16384 * 2);
  ushort* W3T    = (ushort*)alloc(8192 * 2);
  (void)ws_size;

  hipMemsetAsync(ghist, 0, 256 * 4, stream);

  int ntile = (E + PTILE - 1) / PTILE;
  cvt_hist_kernel<<<CVT_BLKS + ntile, 256, 0, stream>>>(
      Wl, Wr, W1, W2, W3, WlT, WrT, W1T, W2T, W3T, ei, ghist, E);

  scan_small_kernel<<<1, 256, 0, stream>>>(ghist, cum, cursor);

  int nblk32 = (N + 31) / 32;
  lin_partition_kernel<<<nblk32 + ntile, 256, 0, stream>>>(
      x, WlT, bl, WrT, br, xlb, xrb, N, nblk32, ei, part, cursor, E);

  fine_kernel<<<nbuck, 512, 0, stream>>>(part, cum, offsets, ssrc, N, E, nbuck);

  int nwblk = (N + 3) / 4;  // 4 waves (nodes) per 256-thread block
  node_aggr_kernel<<<nwblk, 256, 0, stream>>>(xlb, xrb, att, bg,
                                              offsets, ssrc, hbf, N);

  mlp_mfma_kernel<<<nblk32, 256, 0, stream>>>(hbf, W1T, b1, W2T, b2,
                                              W3T, b3, out, N);
}